// Round 1
// baseline (4298.374 us; speedup 1.0000x reference)
//
#include <hip/hip_runtime.h>
#include <math.h>

#define MR_B     16
#define MR_C     256
#define MR_L     8192
#define MR_DEPTH 12
#define TPB      512
#define GPT      (MR_L / 4 / TPB)   // 4 float4 groups per thread

__device__ __forceinline__ float4 f4zero() { return make_float4(0.f, 0.f, 0.f, 0.f); }

__global__ __launch_bounds__(TPB, 4) void multires_fused(
    const float* __restrict__ x,
    const float* __restrict__ h0,
    const float* __restrict__ h1,
    const float* __restrict__ w,
    float* __restrict__ out)
{
    // double-buffered row of res_lo
    __shared__ float buf[2][MR_L];

    const int row = blockIdx.x;        // b*C + c
    const int c   = row & (MR_C - 1);
    const int tid = threadIdx.x;

    // per-channel filters (block-uniform -> scalar loads)
    float f0[4], f1[4];
#pragma unroll
    for (int k = 0; k < 4; ++k) {
        f0[k] = h0[c * 4 + k];
        f1[k] = h1[c * 4 + k];
    }
    float wv[MR_DEPTH + 2];
#pragma unroll
    for (int i = 0; i < MR_DEPTH + 2; ++i) wv[i] = w[c * (MR_DEPTH + 2) + i];

    const float4* __restrict__ xrow = (const float4*)(x + (size_t)row * MR_L);

    float4 res[GPT];   // this thread's current res_lo values (also mirrored in LDS)
    float4 acc[GPT];   // y accumulator

    // load x, init y = x * w[:, -1]
#pragma unroll
    for (int j = 0; j < GPT; ++j) {
        const int g = tid + TPB * j;
        float4 v = xrow[g];
        res[j] = v;
        acc[j].x = v.x * wv[MR_DEPTH + 1];
        acc[j].y = v.y * wv[MR_DEPTH + 1];
        acc[j].z = v.z * wv[MR_DEPTH + 1];
        acc[j].w = v.w * wv[MR_DEPTH + 1];
        ((float4*)buf[0])[g] = v;
    }
    __syncthreads();

    int cur = 0;
#pragma unroll
    for (int lev = 0; lev < MR_DEPTH; ++lev) {
        const int   d  = 1 << lev;
        const float wi = wv[MR_DEPTH - lev];   // w[:, i], i = DEPTH..1
        const float* __restrict__ bc = buf[cur];
        float* __restrict__       bn = buf[cur ^ 1];

#pragma unroll
        for (int j = 0; j < GPT; ++j) {
            const int g = tid + TPB * j;       // float4 group index; covers t = 4g..4g+3
            const float4 rl = res[j];
            float4 t1, t2, t3;                 // taps at t-d, t-2d, t-3d

            if (d == 1) {
                float4 p = (g >= 1) ? ((const float4*)bc)[g - 1] : f4zero();
                t1 = make_float4(p.w, rl.x, rl.y, rl.z);
                t2 = make_float4(p.z, p.w, rl.x, rl.y);
                t3 = make_float4(p.y, p.z, p.w, rl.x);
            } else if (d == 2) {
                float4 p  = (g >= 1) ? ((const float4*)bc)[g - 1] : f4zero();
                float4 p2 = (g >= 2) ? ((const float4*)bc)[g - 2] : f4zero();
                t1 = make_float4(p.z, p.w, rl.x, rl.y);
                t2 = p;
                t3 = make_float4(p2.z, p2.w, p.x, p.y);
            } else {
                const int d4 = d >> 2;         // d % 4 == 0: aligned float4 taps
                t1 = (g >= d4)     ? ((const float4*)bc)[g - d4]     : f4zero();
                t2 = (g >= 2 * d4) ? ((const float4*)bc)[g - 2 * d4] : f4zero();
                t3 = (g >= 3 * d4) ? ((const float4*)bc)[g - 3 * d4] : f4zero();
            }

            // coefficient of x[t - d*j] is h[3-j]
            float4 nl, hi;
            nl.x = f0[3] * rl.x + f0[2] * t1.x + f0[1] * t2.x + f0[0] * t3.x;
            nl.y = f0[3] * rl.y + f0[2] * t1.y + f0[1] * t2.y + f0[0] * t3.y;
            nl.z = f0[3] * rl.z + f0[2] * t1.z + f0[1] * t2.z + f0[0] * t3.z;
            nl.w = f0[3] * rl.w + f0[2] * t1.w + f0[1] * t2.w + f0[0] * t3.w;

            hi.x = f1[3] * rl.x + f1[2] * t1.x + f1[1] * t2.x + f1[0] * t3.x;
            hi.y = f1[3] * rl.y + f1[2] * t1.y + f1[1] * t2.y + f1[0] * t3.y;
            hi.z = f1[3] * rl.z + f1[2] * t1.z + f1[1] * t2.z + f1[0] * t3.z;
            hi.w = f1[3] * rl.w + f1[2] * t1.w + f1[1] * t2.w + f1[0] * t3.w;

            acc[j].x += wi * hi.x;
            acc[j].y += wi * hi.y;
            acc[j].z += wi * hi.z;
            acc[j].w += wi * hi.w;

            res[j] = nl;
            ((float4*)bn)[g] = nl;
        }
        __syncthreads();
        cur ^= 1;
    }

    // epilogue: y += w[:,0] * res_lo; exact GELU; store
    float4* __restrict__ orow = (float4*)(out + (size_t)row * MR_L);
    const float w0 = wv[0];
    const float inv_sqrt2 = 0.70710678118654752f;
#pragma unroll
    for (int j = 0; j < GPT; ++j) {
        const int g = tid + TPB * j;
        float4 v;
        float u;
        u = acc[j].x + w0 * res[j].x; v.x = 0.5f * u * (1.0f + erff(u * inv_sqrt2));
        u = acc[j].y + w0 * res[j].y; v.y = 0.5f * u * (1.0f + erff(u * inv_sqrt2));
        u = acc[j].z + w0 * res[j].z; v.z = 0.5f * u * (1.0f + erff(u * inv_sqrt2));
        u = acc[j].w + w0 * res[j].w; v.w = 0.5f * u * (1.0f + erff(u * inv_sqrt2));
        orow[g] = v;
    }
}

extern "C" void kernel_launch(void* const* d_in, const int* in_sizes, int n_in,
                              void* d_out, int out_size, void* d_ws, size_t ws_size,
                              hipStream_t stream) {
    const float* x  = (const float*)d_in[0];
    const float* h0 = (const float*)d_in[1];
    const float* h1 = (const float*)d_in[2];
    const float* w  = (const float*)d_in[3];
    float* o        = (float*)d_out;

    const int rows = in_sizes[0] / MR_L;   // B*C = 4096
    multires_fused<<<rows, TPB, 0, stream>>>(x, h0, h1, w, o);
}